// Round 1
// baseline (153.196 us; speedup 1.0000x reference)
//
#include <hip/hip_runtime.h>

#define T_ 64
#define S_ 64
#define B_ 128
#define E_ 64
#define H_ 4
#define PR 132   // padded row stride (floats) for [e][*] LDS tiles; %4==0 for float4, +4 breaks bank alias

// ---------------------------------------------------------------------------
// K1: qkv projection. grid 256 blocks x 256 thr; block = 32 rows of (t*b).
// q/k/v computed per segment of in_proj_weight with W^T staged in LDS.
// qkv layout: [3][T][B][E]
// ---------------------------------------------------------------------------
__global__ __launch_bounds__(256) void k_qkv(
    const float* __restrict__ qin, const float* __restrict__ kin,
    const float* __restrict__ vin, const float* __restrict__ W,
    const float* __restrict__ bias, float* __restrict__ qkv)
{
    __shared__ float xs[3][32 * 68];   // [src][row][e], pad 68
    __shared__ float WTs[64 * 68];     // [e][o'] for current segment
    const int tid = threadIdx.x;
    const int row0 = blockIdx.x * 32;

    // stage x for all 3 sources: 3*32*16 = 1536 float4
    #pragma unroll
    for (int l = 0; l < 6; ++l) {
        int f4 = l * 256 + tid;
        int src = f4 >> 9, rem = f4 & 511;
        int r = rem >> 4, e0 = (rem & 15) << 2;
        const float* xin = (src == 0) ? qin : (src == 1 ? kin : vin);
        float4 xv = reinterpret_cast<const float4*>(xin)[(size_t)(row0 + r) * 16 + (e0 >> 2)];
        float* dst = &xs[src][r * 68];
        dst[e0] = xv.x; dst[e0 + 1] = xv.y; dst[e0 + 2] = xv.z; dst[e0 + 3] = xv.w;
    }

    const int rq = tid >> 5, og = tid & 31;
    const int r0 = rq * 4, op0 = og * 2;

    for (int seg = 0; seg < 3; ++seg) {
        __syncthreads();
        // stage W rows [seg*64 .. seg*64+63] transposed: 1024 float4
        #pragma unroll
        for (int l = 0; l < 4; ++l) {
            int f4 = l * 256 + tid;
            int o = f4 >> 4, e0 = (f4 & 15) << 2;
            float4 wv = reinterpret_cast<const float4*>(W)[(size_t)(seg * 64 + o) * 16 + (e0 >> 2)];
            WTs[(e0 + 0) * 68 + o] = wv.x; WTs[(e0 + 1) * 68 + o] = wv.y;
            WTs[(e0 + 2) * 68 + o] = wv.z; WTs[(e0 + 3) * 68 + o] = wv.w;
        }
        __syncthreads();

        float acc[4][2];
        #pragma unroll
        for (int rr = 0; rr < 4; ++rr) {
            acc[rr][0] = bias[seg * 64 + op0];
            acc[rr][1] = bias[seg * 64 + op0 + 1];
        }
        const float* xsrc = xs[seg];
        #pragma unroll 4
        for (int e = 0; e < 64; ++e) {
            float w0 = WTs[e * 68 + op0];
            float w1 = WTs[e * 68 + op0 + 1];
            #pragma unroll
            for (int rr = 0; rr < 4; ++rr) {
                float xv = xsrc[(r0 + rr) * 68 + e];
                acc[rr][0] += xv * w0;
                acc[rr][1] += xv * w1;
            }
        }
        #pragma unroll
        for (int rr = 0; rr < 4; ++rr) {
            float2 ov = make_float2(acc[rr][0], acc[rr][1]);
            reinterpret_cast<float2*>(
                &qkv[((size_t)seg * T_ * B_ + row0 + r0 + rr) * E_ + op0])[0] = ov;
        }
    }
}

// ---------------------------------------------------------------------------
// K2a: fused relation-projection + logits.
// grid = 64 i * 16 jblk = 1024 wgs, 256 thr. Each wg: fixed i, 4 consecutive j.
// logit[i,j,b,h] = (1/16) * sum_n (q[i,b,h16+n]+pa+ba) * (k[j,b,h16+n]+pb+bb)
// where p = relation[j,i,b,:] @ rel_weight.T.
// Thread = (bt: 8 b's, h, ng: 4 n's); accumulates pa[8][4], pb[8][4].
// logits ws layout: [i][b][h][j] (j contiguous for K2b softmax).
// ---------------------------------------------------------------------------
__global__ __launch_bounds__(256) void k_logits(
    const float* __restrict__ rel, const float* __restrict__ relW,
    const float* __restrict__ relBias, const float* __restrict__ qkv,
    float* __restrict__ logits)
{
    __shared__ float WT[64 * PR];        // WT[e][o], o in 0..127   (33792 B)
    __shared__ float rT[32 * PR];        // rT[e_half][b], b 0..127 (16896 B)
    __shared__ float llds[4][B_][H_];    // logits buffer over jj   (8192 B)

    const int tid = threadIdx.x;
    const int i = blockIdx.x >> 4;
    const int jblk = blockIdx.x & 15;
    const int ng = tid & 3;
    const int h = (tid >> 2) & 3;
    const int bt = tid >> 4;
    const int ob = h * 16 + ng * 4;

    // stage rel_weight [128][64] -> WT[e][o]: 2048 float4
    #pragma unroll
    for (int l = 0; l < 8; ++l) {
        int f4 = l * 256 + tid;
        float4 wv = reinterpret_cast<const float4*>(relW)[f4];
        int o = f4 >> 4, e0 = (f4 & 15) << 2;
        WT[(e0 + 0) * PR + o] = wv.x; WT[(e0 + 1) * PR + o] = wv.y;
        WT[(e0 + 2) * PR + o] = wv.z; WT[(e0 + 3) * PR + o] = wv.w;
    }

    float rba[4], rbb[4];
    #pragma unroll
    for (int n = 0; n < 4; ++n) {
        rba[n] = relBias[ob + n];
        rbb[n] = relBias[64 + ob + n];
    }
    const float* qrow = qkv + (size_t)i * B_ * E_;

    for (int jj = 0; jj < 4; ++jj) {
        const int j = jblk * 4 + jj;
        const float4* rsrc =
            reinterpret_cast<const float4*>(rel + ((size_t)j * S_ + i) * B_ * E_);
        float pa[8][4] = {{0.f}}, pb[8][4] = {{0.f}};

        #pragma unroll
        for (int half = 0; half < 2; ++half) {
            __syncthreads();
            // stage relation[j,i,:, e-half] -> rT[e][b]: 1024 float4
            #pragma unroll
            for (int l = 0; l < 4; ++l) {
                int idx = l * 256 + tid;          // 0..1023
                int b = idx >> 3, e0 = (idx & 7) << 2;
                float4 rv = rsrc[b * 16 + half * 8 + (idx & 7)];
                rT[(e0 + 0) * PR + b] = rv.x; rT[(e0 + 1) * PR + b] = rv.y;
                rT[(e0 + 2) * PR + b] = rv.z; rT[(e0 + 3) * PR + b] = rv.w;
            }
            __syncthreads();

            const int ebase = half * 32;
            #pragma unroll 2
            for (int ee = 0; ee < 32; ++ee) {
                const float* Wrow = &WT[(ebase + ee) * PR];
                const float* rrow = &rT[ee * PR + bt * 8];
                float4 wa = *reinterpret_cast<const float4*>(Wrow + ob);
                float4 wb = *reinterpret_cast<const float4*>(Wrow + 64 + ob);
                float4 a0 = *reinterpret_cast<const float4*>(rrow);
                float4 a1 = *reinterpret_cast<const float4*>(rrow + 4);
                float av[8] = {a0.x, a0.y, a0.z, a0.w, a1.x, a1.y, a1.z, a1.w};
                #pragma unroll
                for (int bb = 0; bb < 8; ++bb) {
                    pa[bb][0] += av[bb] * wa.x; pa[bb][1] += av[bb] * wa.y;
                    pa[bb][2] += av[bb] * wa.z; pa[bb][3] += av[bb] * wa.w;
                    pb[bb][0] += av[bb] * wb.x; pb[bb][1] += av[bb] * wb.y;
                    pb[bb][2] += av[bb] * wb.z; pb[bb][3] += av[bb] * wb.w;
                }
            }
        }

        // partial logits + 4-lane reduce over ng
        const float* krow = qkv + ((size_t)T_ * B_ + (size_t)j * B_) * E_;
        #pragma unroll
        for (int bb = 0; bb < 8; ++bb) {
            int b = bt * 8 + bb;
            float4 qv = *reinterpret_cast<const float4*>(qrow + b * E_ + ob);
            float4 kv = *reinterpret_cast<const float4*>(krow + b * E_ + ob);
            float s = (qv.x + pa[bb][0] + rba[0]) * (kv.x + pb[bb][0] + rbb[0])
                    + (qv.y + pa[bb][1] + rba[1]) * (kv.y + pb[bb][1] + rbb[1])
                    + (qv.z + pa[bb][2] + rba[2]) * (kv.z + pb[bb][2] + rbb[2])
                    + (qv.w + pa[bb][3] + rba[3]) * (kv.w + pb[bb][3] + rbb[3]);
            s += __shfl_xor(s, 1);
            s += __shfl_xor(s, 2);
            if (ng == 0) llds[jj][b][h] = s * 0.0625f;
        }
    }
    __syncthreads();

    // flush: logits[i][b][h][jblk*4 .. +3]
    #pragma unroll
    for (int p = tid; p < B_ * H_; p += 256) {
        int b = p >> 2, hh = p & 3;
        float4 lv = make_float4(llds[0][b][hh], llds[1][b][hh],
                                llds[2][b][hh], llds[3][b][hh]);
        reinterpret_cast<float4*>(
            &logits[(((size_t)i * B_ + b) * H_ + hh) * T_ + jblk * 4])[0] = lv;
    }
}

// ---------------------------------------------------------------------------
// K2b: softmax over j + PV + out-projection.
// grid = 64 i * 32 bq = 2048 blocks, 256 thr = 4 waves; wave w -> b = bq*4+w.
// ---------------------------------------------------------------------------
__global__ __launch_bounds__(256) void k_attn(
    const float* __restrict__ logits, const float* __restrict__ qkv,
    const float* __restrict__ Wout, const float* __restrict__ bout,
    float* __restrict__ out)
{
    __shared__ float wsm[4][H_][S_];
    __shared__ float ap[4][68];
    const int tid = threadIdx.x;
    const int i = blockIdx.x >> 5;
    const int bq = blockIdx.x & 31;
    const int w = tid >> 6, l = tid & 63;
    const int b = bq * 4 + w;

    // softmax: lane group h = l>>4 handles j = {sub, sub+16, sub+32, sub+48}
    const float* lg = logits + ((size_t)i * B_ + b) * H_ * S_;
    const int h = l >> 4, sub = l & 15;
    float v0 = lg[h * S_ + sub];
    float v1 = lg[h * S_ + sub + 16];
    float v2 = lg[h * S_ + sub + 32];
    float v3 = lg[h * S_ + sub + 48];
    float m = fmaxf(fmaxf(v0, v1), fmaxf(v2, v3));
    #pragma unroll
    for (int d = 1; d < 16; d <<= 1) m = fmaxf(m, __shfl_xor(m, d));
    float e0 = expf(v0 - m), e1 = expf(v1 - m), e2 = expf(v2 - m), e3 = expf(v3 - m);
    float ss = e0 + e1 + e2 + e3;
    #pragma unroll
    for (int d = 1; d < 16; d <<= 1) ss += __shfl_xor(ss, d);
    float inv = 1.0f / ss;
    wsm[w][h][sub] = e0 * inv;
    wsm[w][h][sub + 16] = e1 * inv;
    wsm[w][h][sub + 32] = e2 * inv;
    wsm[w][h][sub + 48] = e3 * inv;
    __syncthreads();

    // PV: lane l computes attn_pre[e=l]
    const float* vbase = qkv + (size_t)2 * T_ * B_ * E_ + (size_t)b * E_;
    const float* wrow = &wsm[w][l >> 4][0];
    float acc = 0.f;
    #pragma unroll 4
    for (int j = 0; j < S_; ++j) acc += wrow[j] * vbase[(size_t)j * B_ * E_ + l];
    ap[w][l] = acc;
    __syncthreads();

    // out-proj: lane l computes out[i][b][l]
    const float* wo = Wout + l * E_;
    const float* apw = ap[w];
    float oacc = bout[l];
    #pragma unroll 4
    for (int e = 0; e < E_; ++e) oacc += apw[e] * wo[e];
    out[((size_t)i * B_ + b) * E_ + l] = oacc;
}

// ---------------------------------------------------------------------------
extern "C" void kernel_launch(void* const* d_in, const int* in_sizes, int n_in,
                              void* d_out, int out_size, void* d_ws, size_t ws_size,
                              hipStream_t stream)
{
    const float* qin = (const float*)d_in[0];
    const float* kin = (const float*)d_in[1];
    const float* vin = (const float*)d_in[2];
    const float* rel = (const float*)d_in[3];
    const float* ipw = (const float*)d_in[4];
    const float* ipb = (const float*)d_in[5];
    const float* rw  = (const float*)d_in[6];
    const float* rb  = (const float*)d_in[7];
    const float* ow  = (const float*)d_in[8];
    const float* obias = (const float*)d_in[9];

    float* qkv = (float*)d_ws;                       // 3*64*128*64 fl = 6 MB
    float* logits = qkv + 3 * T_ * B_ * E_;          // 64*128*4*64 fl = 8 MB
    float* out = (float*)d_out;

    k_qkv<<<dim3(256), dim3(256), 0, stream>>>(qin, kin, vin, ipw, ipb, qkv);
    k_logits<<<dim3(1024), dim3(256), 0, stream>>>(rel, rw, rb, qkv, logits);
    k_attn<<<dim3(2048), dim3(256), 0, stream>>>(logits, qkv, ow, obias, out);
}

// Round 2
// 98.351 us; speedup vs baseline: 1.5577x; 1.5577x over previous
//
#include <hip/hip_runtime.h>
#include <hip/hip_bf16.h>

#define T_ 64
#define S_ 64
#define B_ 128
#define E_ 64
#define H_ 4

typedef float f32x4 __attribute__((ext_vector_type(4)));
typedef short bf16x8 __attribute__((ext_vector_type(8)));

static __device__ __forceinline__ short f2b(float f) {
    union { __hip_bfloat16 h; short s; } u;
    u.h = __float2bfloat16(f);
    return u.s;
}

// ---------------------------------------------------------------------------
// K1: qkv projection (unchanged from round 1). qkv layout: [3][T][B][E]
// ---------------------------------------------------------------------------
__global__ __launch_bounds__(256) void k_qkv(
    const float* __restrict__ qin, const float* __restrict__ kin,
    const float* __restrict__ vin, const float* __restrict__ W,
    const float* __restrict__ bias, float* __restrict__ qkv)
{
    __shared__ float xs[3][32 * 68];
    __shared__ float WTs[64 * 68];
    const int tid = threadIdx.x;
    const int row0 = blockIdx.x * 32;

    #pragma unroll
    for (int l = 0; l < 6; ++l) {
        int f4 = l * 256 + tid;
        int src = f4 >> 9, rem = f4 & 511;
        int r = rem >> 4, e0 = (rem & 15) << 2;
        const float* xin = (src == 0) ? qin : (src == 1 ? kin : vin);
        float4 xv = reinterpret_cast<const float4*>(xin)[(size_t)(row0 + r) * 16 + (e0 >> 2)];
        float* dst = &xs[src][r * 68];
        dst[e0] = xv.x; dst[e0 + 1] = xv.y; dst[e0 + 2] = xv.z; dst[e0 + 3] = xv.w;
    }

    const int rq = tid >> 5, og = tid & 31;
    const int r0 = rq * 4, op0 = og * 2;

    for (int seg = 0; seg < 3; ++seg) {
        __syncthreads();
        #pragma unroll
        for (int l = 0; l < 4; ++l) {
            int f4 = l * 256 + tid;
            int o = f4 >> 4, e0 = (f4 & 15) << 2;
            float4 wv = reinterpret_cast<const float4*>(W)[(size_t)(seg * 64 + o) * 16 + (e0 >> 2)];
            WTs[(e0 + 0) * 68 + o] = wv.x; WTs[(e0 + 1) * 68 + o] = wv.y;
            WTs[(e0 + 2) * 68 + o] = wv.z; WTs[(e0 + 3) * 68 + o] = wv.w;
        }
        __syncthreads();

        float acc[4][2];
        #pragma unroll
        for (int rr = 0; rr < 4; ++rr) {
            acc[rr][0] = bias[seg * 64 + op0];
            acc[rr][1] = bias[seg * 64 + op0 + 1];
        }
        const float* xsrc = xs[seg];
        #pragma unroll 4
        for (int e = 0; e < 64; ++e) {
            float w0 = WTs[e * 68 + op0];
            float w1 = WTs[e * 68 + op0 + 1];
            #pragma unroll
            for (int rr = 0; rr < 4; ++rr) {
                float xv = xsrc[(r0 + rr) * 68 + e];
                acc[rr][0] += xv * w0;
                acc[rr][1] += xv * w1;
            }
        }
        #pragma unroll
        for (int rr = 0; rr < 4; ++rr) {
            float2 ov = make_float2(acc[rr][0], acc[rr][1]);
            reinterpret_cast<float2*>(
                &qkv[((size_t)seg * T_ * B_ + row0 + r0 + rr) * E_ + op0])[0] = ov;
        }
    }
}

// ---------------------------------------------------------------------------
// K2a (MFMA rewrite): fused relation-projection + logits.
// grid = 64 i * 4 jq = 256 wgs, 512 thr = 8 waves. Wave w owns b-tile w (16 b),
// all 128 o, 16 j's. Per j: P[b][o] = rel[j,i,b,:] @ relW[o,:] via
// mfma_f32_16x16x32_bf16 (8 o-tiles x 2 k-steps), then
// logit[i,b,h,j] = (1/16) * sum_n (q+pa+ba)(k+pb+bb), n-reduce over lanes 0..15.
//
// A: fp32 in LDS via global_load_lds(16B), double-buffered, 32B-chunk XOR
//    swizzle applied on the GLOBAL SOURCE address (linear LDS dest).
// B: relW as bf16 in LDS, 16B-chunk XOR swizzle, staged once.
// No barriers in the j loop: each wave stages/reads only its own A rows;
// counted vmcnt(4) keeps the next j's 4 loads in flight during compute.
// ---------------------------------------------------------------------------
__global__ __launch_bounds__(512, 2) void k_logits_mfma(
    const float* __restrict__ rel, const float* __restrict__ relW,
    const float* __restrict__ relBias, const float* __restrict__ qkv,
    float* __restrict__ logits)
{
    __shared__ ushort Bs[128 * 64];      // bf16 W, swizzled       (16 KB)
    __shared__ float  As[2][128 * 64];   // fp32 rel, swizzled     (2x32 KB)

    const int tid = threadIdx.x;
    const int w   = tid >> 6;
    const int l   = tid & 63;
    const int c   = l & 15;      // MFMA col / n-within-head
    const int rq  = l >> 4;      // MFMA row-quadrant / k-group
    const int i   = blockIdx.x >> 2;
    const int jb  = (blockIdx.x & 3) * 16;

    // ---- stage relW -> Bs (bf16, chunk^row swizzle) ----
    #pragma unroll
    for (int li = 0; li < 4; ++li) {
        int f4 = li * 512 + tid;             // 0..2047
        int o = f4 >> 4, e4 = f4 & 15;       // o row, 4-float chunk
        float4 wv = reinterpret_cast<const float4*>(relW)[f4];
        ushort4 bv;
        bv.x = (ushort)f2b(wv.x); bv.y = (ushort)f2b(wv.y);
        bv.z = (ushort)f2b(wv.z); bv.w = (ushort)f2b(wv.w);
        int byteoff = o * 128 + (((e4 >> 1) ^ (o & 7)) << 4) + ((e4 & 1) << 3);
        *reinterpret_cast<ushort4*>(reinterpret_cast<char*>(Bs) + byteoff) = bv;
    }

    // ---- hoist q + rel biases into registers ----
    float qpre[4][4], bbv[4];
    {
        const float* qrow = qkv + (size_t)i * (B_ * E_);
        #pragma unroll
        for (int h = 0; h < 4; ++h) {
            float ba = relBias[h * 16 + c];
            bbv[h] = relBias[64 + h * 16 + c];
            #pragma unroll
            for (int r = 0; r < 4; ++r) {
                int b = w * 16 + rq * 4 + r;
                qpre[h][r] = qrow[b * E_ + h * 16 + c] + ba;
            }
        }
    }
    __syncthreads();   // Bs ready

// stage rel[j,i] rows [w*16 .. w*16+15] into As[buf] (this wave's region only).
// dest byte = w*4096 + it*1024 + lane*16  -> row = w*16+it*4+(lane>>4),
// phys 32B chunk p=(lane&15)>>1, half=lane&1; source fetches logical chunk
// p^(row&7) so that swizzled reads below see logical data.
#define STAGE(jj, bufi)                                                        \
    {                                                                          \
        const char* srcb = (const char*)(rel + ((size_t)(jj) * S_ + i) * (size_t)(B_ * E_)); \
        char* dstb = (char*)&As[bufi][0] + w * 4096;                           \
        _Pragma("unroll")                                                      \
        for (int it = 0; it < 4; ++it) {                                       \
            int row = w * 16 + it * 4 + (l >> 4);                              \
            int srcoff = row * 256 + (((((l & 15) >> 1)) ^ (row & 7)) << 5) + ((l & 1) << 4); \
            __builtin_amdgcn_global_load_lds(                                  \
                (const __attribute__((address_space(1))) void*)(srcb + srcoff),\
                (__attribute__((address_space(3))) void*)(dstb + it * 1024),   \
                16, 0, 0);                                                     \
        }                                                                      \
    }

    int buf = 0;
    STAGE(jb, 0);

    #pragma unroll 1
    for (int t = 0; t < 16; ++t) {
        if (t < 15) {
            STAGE(jb + t + 1, buf ^ 1);
            // drain everything except the 4 newest (the j+1 stage) -> j's tile ready
            asm volatile("s_waitcnt vmcnt(4) lgkmcnt(0)" ::: "memory");
        } else {
            asm volatile("s_waitcnt vmcnt(0) lgkmcnt(0)" ::: "memory");
        }
        const int j = jb + t;

        // k-values for epilogue (issued early, consumed late)
        float kvv[4][4];
        {
            const float* krow = qkv + ((size_t)(T_ * B_) + (size_t)j * B_) * E_;
            #pragma unroll
            for (int h = 0; h < 4; ++h)
                #pragma unroll
                for (int r = 0; r < 4; ++r)
                    kvv[h][r] = krow[(w * 16 + rq * 4 + r) * E_ + h * 16 + c];
        }

        // A fragments: row = w*16 + c, k-chunk = ks*4 + rq (swizzled), fp32->bf16
        bf16x8 af[2];
        {
            int row = w * 16 + c;
            const char* abase = (const char*)&As[buf][0] + row * 256;
            #pragma unroll
            for (int ks = 0; ks < 2; ++ks) {
                int chunk = (ks * 4 + rq) ^ (row & 7);
                const float4* ap = (const float4*)(abase + chunk * 32);
                float4 x0 = ap[0];
                float4 x1 = ap[1];
                bf16x8 a;
                a[0] = f2b(x0.x); a[1] = f2b(x0.y); a[2] = f2b(x0.z); a[3] = f2b(x0.w);
                a[4] = f2b(x1.x); a[5] = f2b(x1.y); a[6] = f2b(x1.z); a[7] = f2b(x1.w);
                af[ks] = a;
            }
        }

        // GEMM: 8 o-tiles x 2 k-steps
        f32x4 acc[8];
        #pragma unroll
        for (int ot = 0; ot < 8; ++ot) acc[ot] = (f32x4){0.f, 0.f, 0.f, 0.f};
        #pragma unroll
        for (int ot = 0; ot < 8; ++ot) {
            int br = ot * 16 + c;
            const char* bbase = (const char*)Bs + br * 128;
            #pragma unroll
            for (int ks = 0; ks < 2; ++ks) {
                int chunk = (ks * 4 + rq) ^ (br & 7);
                bf16x8 bfr = *(const bf16x8*)(bbase + chunk * 16);
                acc[ot] = __builtin_amdgcn_mfma_f32_16x16x32_bf16(af[ks], bfr, acc[ot], 0, 0, 0);
            }
        }

        // epilogue: logit = (1/16) * sum_n (q+pa+ba)(k+pb+bb); reduce n over c
        float outv = 0.f;
        #pragma unroll
        for (int h = 0; h < 4; ++h) {
            #pragma unroll
            for (int r = 0; r < 4; ++r) {
                float s = (qpre[h][r] + acc[h][r]) * (kvv[h][r] + bbv[h] + acc[4 + h][r]);
                s += __shfl_xor(s, 1);
                s += __shfl_xor(s, 2);
                s += __shfl_xor(s, 4);
                s += __shfl_xor(s, 8);
                if (c == h * 4 + r) outv = s * 0.0625f;
            }
        }
        {
            int hh = c >> 2, rr = c & 3;
            int b = w * 16 + rq * 4 + rr;
            logits[(((size_t)i * B_ + b) * H_ + hh) * S_ + j] = outv;
        }
        buf ^= 1;
    }
#undef STAGE
}

// ---------------------------------------------------------------------------
// K2b: softmax over j + PV + out-projection (unchanged from round 1).
// ---------------------------------------------------------------------------
__global__ __launch_bounds__(256) void k_attn(
    const float* __restrict__ logits, const float* __restrict__ qkv,
    const float* __restrict__ Wout, const float* __restrict__ bout,
    float* __restrict__ out)
{
    __shared__ float wsm[4][H_][S_];
    __shared__ float ap[4][68];
    const int tid = threadIdx.x;
    const int i = blockIdx.x >> 5;
    const int bq = blockIdx.x & 31;
    const int w = tid >> 6, l = tid & 63;
    const int b = bq * 4 + w;

    const float* lg = logits + ((size_t)i * B_ + b) * H_ * S_;
    const int h = l >> 4, sub = l & 15;
    float v0 = lg[h * S_ + sub];
    float v1 = lg[h * S_ + sub + 16];
    float v2 = lg[h * S_ + sub + 32];
    float v3 = lg[h * S_ + sub + 48];
    float m = fmaxf(fmaxf(v0, v1), fmaxf(v2, v3));
    #pragma unroll
    for (int d = 1; d < 16; d <<= 1) m = fmaxf(m, __shfl_xor(m, d));
    float e0 = expf(v0 - m), e1 = expf(v1 - m), e2 = expf(v2 - m), e3 = expf(v3 - m);
    float ss = e0 + e1 + e2 + e3;
    #pragma unroll
    for (int d = 1; d < 16; d <<= 1) ss += __shfl_xor(ss, d);
    float inv = 1.0f / ss;
    wsm[w][h][sub] = e0 * inv;
    wsm[w][h][sub + 16] = e1 * inv;
    wsm[w][h][sub + 32] = e2 * inv;
    wsm[w][h][sub + 48] = e3 * inv;
    __syncthreads();

    const float* vbase = qkv + (size_t)2 * T_ * B_ * E_ + (size_t)b * E_;
    const float* wrow = &wsm[w][l >> 4][0];
    float acc = 0.f;
    #pragma unroll 4
    for (int j = 0; j < S_; ++j) acc += wrow[j] * vbase[(size_t)j * B_ * E_ + l];
    ap[w][l] = acc;
    __syncthreads();

    const float* wo = Wout + l * E_;
    const float* apw = ap[w];
    float oacc = bout[l];
    #pragma unroll 4
    for (int e = 0; e < E_; ++e) oacc += apw[e] * wo[e];
    out[((size_t)i * B_ + b) * E_ + l] = oacc;
}

// ---------------------------------------------------------------------------
extern "C" void kernel_launch(void* const* d_in, const int* in_sizes, int n_in,
                              void* d_out, int out_size, void* d_ws, size_t ws_size,
                              hipStream_t stream)
{
    const float* qin = (const float*)d_in[0];
    const float* kin = (const float*)d_in[1];
    const float* vin = (const float*)d_in[2];
    const float* rel = (const float*)d_in[3];
    const float* ipw = (const float*)d_in[4];
    const float* ipb = (const float*)d_in[5];
    const float* rw  = (const float*)d_in[6];
    const float* rb  = (const float*)d_in[7];
    const float* ow  = (const float*)d_in[8];
    const float* obias = (const float*)d_in[9];

    float* qkv = (float*)d_ws;                       // 3*64*128*64 fl = 6 MB
    float* logits = qkv + 3 * T_ * B_ * E_;          // 64*128*4*64 fl = 8 MB
    float* out = (float*)d_out;

    k_qkv<<<dim3(256), dim3(256), 0, stream>>>(qin, kin, vin, ipw, ipb, qkv);
    k_logits_mfma<<<dim3(256), dim3(512), 0, stream>>>(rel, rw, rb, qkv, logits);
    k_attn<<<dim3(2048), dim3(256), 0, stream>>>(logits, qkv, ow, obias, out);
}

// Round 3
// 71.316 us; speedup vs baseline: 2.1481x; 1.3791x over previous
//
#include <hip/hip_runtime.h>
#include <hip/hip_bf16.h>

#define T_ 64
#define S_ 64
#define B_ 128
#define E_ 64
#define H_ 4

typedef float f32x4 __attribute__((ext_vector_type(4)));
typedef short bf16x8 __attribute__((ext_vector_type(8)));

static __device__ __forceinline__ short f2b(float f) {
    union { __hip_bfloat16 h; short s; } u;
    u.h = __float2bfloat16(f);
    return u.s;
}

// ---------------------------------------------------------------------------
// K1: qkv projection (unchanged). qkv layout: [3][T][B][E]
// ---------------------------------------------------------------------------
__global__ __launch_bounds__(256) void k_qkv(
    const float* __restrict__ qin, const float* __restrict__ kin,
    const float* __restrict__ vin, const float* __restrict__ W,
    const float* __restrict__ bias, float* __restrict__ qkv)
{
    __shared__ float xs[3][32 * 68];
    __shared__ float WTs[64 * 68];
    const int tid = threadIdx.x;
    const int row0 = blockIdx.x * 32;

    #pragma unroll
    for (int l = 0; l < 6; ++l) {
        int f4 = l * 256 + tid;
        int src = f4 >> 9, rem = f4 & 511;
        int r = rem >> 4, e0 = (rem & 15) << 2;
        const float* xin = (src == 0) ? qin : (src == 1 ? kin : vin);
        float4 xv = reinterpret_cast<const float4*>(xin)[(size_t)(row0 + r) * 16 + (e0 >> 2)];
        float* dst = &xs[src][r * 68];
        dst[e0] = xv.x; dst[e0 + 1] = xv.y; dst[e0 + 2] = xv.z; dst[e0 + 3] = xv.w;
    }

    const int rq = tid >> 5, og = tid & 31;
    const int r0 = rq * 4, op0 = og * 2;

    for (int seg = 0; seg < 3; ++seg) {
        __syncthreads();
        #pragma unroll
        for (int l = 0; l < 4; ++l) {
            int f4 = l * 256 + tid;
            int o = f4 >> 4, e0 = (f4 & 15) << 2;
            float4 wv = reinterpret_cast<const float4*>(W)[(size_t)(seg * 64 + o) * 16 + (e0 >> 2)];
            WTs[(e0 + 0) * 68 + o] = wv.x; WTs[(e0 + 1) * 68 + o] = wv.y;
            WTs[(e0 + 2) * 68 + o] = wv.z; WTs[(e0 + 3) * 68 + o] = wv.w;
        }
        __syncthreads();

        float acc[4][2];
        #pragma unroll
        for (int rr = 0; rr < 4; ++rr) {
            acc[rr][0] = bias[seg * 64 + op0];
            acc[rr][1] = bias[seg * 64 + op0 + 1];
        }
        const float* xsrc = xs[seg];
        #pragma unroll 4
        for (int e = 0; e < 64; ++e) {
            float w0 = WTs[e * 68 + op0];
            float w1 = WTs[e * 68 + op0 + 1];
            #pragma unroll
            for (int rr = 0; rr < 4; ++rr) {
                float xv = xsrc[(r0 + rr) * 68 + e];
                acc[rr][0] += xv * w0;
                acc[rr][1] += xv * w1;
            }
        }
        #pragma unroll
        for (int rr = 0; rr < 4; ++rr) {
            float2 ov = make_float2(acc[rr][0], acc[rr][1]);
            reinterpret_cast<float2*>(
                &qkv[((size_t)seg * T_ * B_ + row0 + r0 + rr) * E_ + op0])[0] = ov;
        }
    }
}

// ---------------------------------------------------------------------------
// K2a: fused relation-projection + logits (MFMA).
// grid = 64 i * 8 jq = 512 wgs, 512 thr = 8 waves, 2 wg/CU. Wave w owns b-tile
// w (16 b), all 128 o, 8 j's. Per j: P[b][o] = rel[j,i,b,:] @ relW[o,:] via
// mfma_f32_16x16x32_bf16 (8 o-tiles x 2 k-steps); epilogue computes
// logit = (1/16) sum_n (q+pa+ba)(k+pb+bb) with a 15-shfl butterfly
// reduce-scatter; logits buffered in regs, flushed coalesced at the end.
//
// A: fp32 via global_load_lds(16B), double-buffered; 16B-unit XOR swizzle
//    (u ^= row&7) applied on the GLOBAL SOURCE address, linear LDS dest.
// B: bf16, fragment-linear layout (frag(ot,ks) at (ot*2+ks)*1024 + lane*16).
// No barriers in the j loop (each wave stages/reads only its own A rows);
// counted vmcnt(4) keeps next-j loads in flight during compute.
// ---------------------------------------------------------------------------
__global__ __launch_bounds__(512, 4) void k_logits_mfma(
    const float* __restrict__ rel, const float* __restrict__ relW,
    const float* __restrict__ relBias, const float* __restrict__ qkv,
    float* __restrict__ logits)
{
    __shared__ char  Bs[16384];          // bf16 W, fragment-linear (16 KB)
    __shared__ float As[2][128 * 64];    // fp32 rel, swizzled      (2x32 KB)

    const int tid = threadIdx.x;
    const int w   = tid >> 6;
    const int l   = tid & 63;
    const int c   = l & 15;      // MFMA col lane
    const int rq  = l >> 4;      // MFMA row-quadrant / k-subchunk
    const int i   = blockIdx.x >> 3;
    const int jb  = (blockIdx.x & 7) * 8;

    // ---- stage relW -> Bs (bf16, fragment-linear) ----
    #pragma unroll
    for (int li = 0; li < 4; ++li) {
        int f4 = li * 512 + tid;             // 0..2047 = o*16 + e4
        int o = f4 >> 4, e4 = f4 & 15;
        float4 wv = reinterpret_cast<const float4*>(relW)[f4];
        ushort4 bv;
        bv.x = (ushort)f2b(wv.x); bv.y = (ushort)f2b(wv.y);
        bv.z = (ushort)f2b(wv.z); bv.w = (ushort)f2b(wv.w);
        int ot = o >> 4, cc = o & 15;
        int ks = e4 >> 3, rqb = (e4 & 7) >> 1, half = e4 & 1;
        int dest = (ot * 2 + ks) * 1024 + (rqb * 16 + cc) * 16 + half * 8;
        *reinterpret_cast<ushort4*>(Bs + dest) = bv;
    }

    // ---- hoist q + rel biases into registers ----
    float qpre[4][4], bbv[4];
    {
        const float* qrow = qkv + (size_t)i * (B_ * E_);
        #pragma unroll
        for (int h = 0; h < 4; ++h) {
            float ba = relBias[h * 16 + c];
            bbv[h] = relBias[64 + h * 16 + c];
            #pragma unroll
            for (int r = 0; r < 4; ++r) {
                int b = w * 16 + rq * 4 + r;
                qpre[h][r] = qrow[b * E_ + h * 16 + c] + ba;
            }
        }
    }
    __syncthreads();   // Bs ready

// stage rel[j,i] rows [w*16..w*16+15] into As[bufi] (this wave's region only).
// dest byte = w*4096 + it*1024 + lane*16 -> row = w*16+it*4+(lane>>4),
// phys 16B-unit p = lane&15; source supplies logical unit u = p ^ (row&7).
#define STAGE(jj, bufi)                                                        \
    {                                                                          \
        const char* srcb = (const char*)(rel + ((size_t)(jj) * S_ + i) * (size_t)(B_ * E_)); \
        char* dstb = (char*)&As[bufi][0] + w * 4096;                           \
        _Pragma("unroll")                                                      \
        for (int it = 0; it < 4; ++it) {                                       \
            int row = w * 16 + it * 4 + (l >> 4);                              \
            int srcoff = row * 256 + (((l & 15) ^ (row & 7)) << 4);            \
            __builtin_amdgcn_global_load_lds(                                  \
                (const __attribute__((address_space(1))) void*)(srcb + srcoff),\
                (__attribute__((address_space(3))) void*)(dstb + it * 1024),   \
                16, 0, 0);                                                     \
        }                                                                      \
    }

    float lbuf[8];
    int buf = 0;
    STAGE(jb, 0);

    #pragma unroll 1
    for (int t = 0; t < 8; ++t) {
        if (t < 7) {
            STAGE(jb + t + 1, buf ^ 1);
            asm volatile("s_waitcnt vmcnt(4) lgkmcnt(0)" ::: "memory");
        } else {
            asm volatile("s_waitcnt vmcnt(0) lgkmcnt(0)" ::: "memory");
        }
        const int j = jb + t;

        // k-values for epilogue (L2 hits, hidden under MFMA)
        float kvv[4][4];
        {
            const float* krow = qkv + ((size_t)(T_ * B_) + (size_t)j * B_) * E_;
            #pragma unroll
            for (int h = 0; h < 4; ++h)
                #pragma unroll
                for (int r = 0; r < 4; ++r)
                    kvv[h][r] = krow[(w * 16 + rq * 4 + r) * E_ + h * 16 + c];
        }

        // A fragments: row = w*16+c; units (ks*8+rq*2+{0,1}) ^ (c&7)
        bf16x8 af[2];
        {
            const int row = w * 16 + c;
            const char* abase = (const char*)&As[buf][0] + row * 256;
            const int s7 = c & 7;
            #pragma unroll
            for (int ks = 0; ks < 2; ++ks) {
                float4 x0 = *(const float4*)(abase + (((ks * 8 + rq * 2 + 0) ^ s7) << 4));
                float4 x1 = *(const float4*)(abase + (((ks * 8 + rq * 2 + 1) ^ s7) << 4));
                bf16x8 a;
                a[0] = f2b(x0.x); a[1] = f2b(x0.y); a[2] = f2b(x0.z); a[3] = f2b(x0.w);
                a[4] = f2b(x1.x); a[5] = f2b(x1.y); a[6] = f2b(x1.z); a[7] = f2b(x1.w);
                af[ks] = a;
            }
        }

        // GEMM: 8 o-tiles x 2 k-steps; B reads are lane-linear (conflict-free)
        f32x4 acc[8];
        #pragma unroll
        for (int ot = 0; ot < 8; ++ot) acc[ot] = (f32x4){0.f, 0.f, 0.f, 0.f};
        #pragma unroll
        for (int ot = 0; ot < 8; ++ot) {
            #pragma unroll
            for (int ks = 0; ks < 2; ++ks) {
                bf16x8 bfr = *(const bf16x8*)(Bs + (ot * 2 + ks) * 1024 + l * 16);
                acc[ot] = __builtin_amdgcn_mfma_f32_16x16x32_bf16(af[ks], bfr, acc[ot], 0, 0, 0);
            }
        }

        // epilogue: v[idx=h*4+r] per lane; butterfly reduce-scatter over c-lanes
        // so lane c ends with the full n-sum for idx == c.
        float v[16];
        #pragma unroll
        for (int h = 0; h < 4; ++h)
            #pragma unroll
            for (int r = 0; r < 4; ++r)
                v[h * 4 + r] = (qpre[h][r] + acc[h][r]) *
                               (kvv[h][r] + bbv[h] + acc[4 + h][r]);
        #pragma unroll
        for (int k = 0; k < 8; ++k) {
            float x = (c & 1) ? v[2 * k + 1] : v[2 * k];
            float y = (c & 1) ? v[2 * k] : v[2 * k + 1];
            v[k] = x + __shfl_xor(y, 1);
        }
        #pragma unroll
        for (int k = 0; k < 4; ++k) {
            float x = (c & 2) ? v[2 * k + 1] : v[2 * k];
            float y = (c & 2) ? v[2 * k] : v[2 * k + 1];
            v[k] = x + __shfl_xor(y, 2);
        }
        #pragma unroll
        for (int k = 0; k < 2; ++k) {
            float x = (c & 4) ? v[2 * k + 1] : v[2 * k];
            float y = (c & 4) ? v[2 * k] : v[2 * k + 1];
            v[k] = x + __shfl_xor(y, 4);
        }
        {
            float x = (c & 8) ? v[1] : v[0];
            float y = (c & 8) ? v[0] : v[1];
            lbuf[t] = (x + __shfl_xor(y, 8)) * 0.0625f;
        }
        buf ^= 1;
    }
#undef STAGE

    // flush: lane (w,rq,c) owns logits[i][b = w*16+rq*4+(c&3)][h = c>>2][jb..jb+7]
    {
        const int hh = c >> 2, rr = c & 3;
        const int b = w * 16 + rq * 4 + rr;
        float* dst = &logits[(((size_t)i * B_ + b) * H_ + hh) * S_ + jb];
        *reinterpret_cast<float4*>(dst) = make_float4(lbuf[0], lbuf[1], lbuf[2], lbuf[3]);
        *reinterpret_cast<float4*>(dst + 4) = make_float4(lbuf[4], lbuf[5], lbuf[6], lbuf[7]);
    }
}

// ---------------------------------------------------------------------------
// K2b: softmax over j + PV + out-projection (unchanged).
// ---------------------------------------------------------------------------
__global__ __launch_bounds__(256) void k_attn(
    const float* __restrict__ logits, const float* __restrict__ qkv,
    const float* __restrict__ Wout, const float* __restrict__ bout,
    float* __restrict__ out)
{
    __shared__ float wsm[4][H_][S_];
    __shared__ float ap[4][68];
    const int tid = threadIdx.x;
    const int i = blockIdx.x >> 5;
    const int bq = blockIdx.x & 31;
    const int w = tid >> 6, l = tid & 63;
    const int b = bq * 4 + w;

    const float* lg = logits + ((size_t)i * B_ + b) * H_ * S_;
    const int h = l >> 4, sub = l & 15;
    float v0 = lg[h * S_ + sub];
    float v1 = lg[h * S_ + sub + 16];
    float v2 = lg[h * S_ + sub + 32];
    float v3 = lg[h * S_ + sub + 48];
    float m = fmaxf(fmaxf(v0, v1), fmaxf(v2, v3));
    #pragma unroll
    for (int d = 1; d < 16; d <<= 1) m = fmaxf(m, __shfl_xor(m, d));
    float e0 = expf(v0 - m), e1 = expf(v1 - m), e2 = expf(v2 - m), e3 = expf(v3 - m);
    float ss = e0 + e1 + e2 + e3;
    #pragma unroll
    for (int d = 1; d < 16; d <<= 1) ss += __shfl_xor(ss, d);
    float inv = 1.0f / ss;
    wsm[w][h][sub] = e0 * inv;
    wsm[w][h][sub + 16] = e1 * inv;
    wsm[w][h][sub + 32] = e2 * inv;
    wsm[w][h][sub + 48] = e3 * inv;
    __syncthreads();

    const float* vbase = qkv + (size_t)2 * T_ * B_ * E_ + (size_t)b * E_;
    const float* wrow = &wsm[w][l >> 4][0];
    float acc = 0.f;
    #pragma unroll 4
    for (int j = 0; j < S_; ++j) acc += wrow[j] * vbase[(size_t)j * B_ * E_ + l];
    ap[w][l] = acc;
    __syncthreads();

    const float* wo = Wout + l * E_;
    const float* apw = ap[w];
    float oacc = bout[l];
    #pragma unroll 4
    for (int e = 0; e < E_; ++e) oacc += apw[e] * wo[e];
    out[((size_t)i * B_ + b) * E_ + l] = oacc;
}

// ---------------------------------------------------------------------------
extern "C" void kernel_launch(void* const* d_in, const int* in_sizes, int n_in,
                              void* d_out, int out_size, void* d_ws, size_t ws_size,
                              hipStream_t stream)
{
    const float* qin = (const float*)d_in[0];
    const float* kin = (const float*)d_in[1];
    const float* vin = (const float*)d_in[2];
    const float* rel = (const float*)d_in[3];
    const float* ipw = (const float*)d_in[4];
    const float* ipb = (const float*)d_in[5];
    const float* rw  = (const float*)d_in[6];
    const float* rb  = (const float*)d_in[7];
    const float* ow  = (const float*)d_in[8];
    const float* obias = (const float*)d_in[9];

    float* qkv = (float*)d_ws;                       // 3*64*128*64 fl = 6 MB
    float* logits = qkv + 3 * T_ * B_ * E_;          // 64*128*4*64 fl = 8 MB
    float* out = (float*)d_out;

    k_qkv<<<dim3(256), dim3(256), 0, stream>>>(qin, kin, vin, ipw, ipb, qkv);
    k_logits_mfma<<<dim3(512), dim3(512), 0, stream>>>(rel, rw, rb, qkv, logits);
    k_attn<<<dim3(2048), dim3(256), 0, stream>>>(logits, qkv, ow, obias, out);
}